// Round 4
// baseline (3885.004 us; speedup 1.0000x reference)
//
#include <hip/hip_runtime.h>

constexpr int NUM_USER  = 100000;
constexpr int NUM_ITEM  = 50000;
constexpr int DIM       = 64;
constexpr int NUM_EDGES = 3200000;

constexpr int KPB  = 64;                              // keys per bucket
constexpr int NB_U = (NUM_USER + KPB - 1) / KPB;      // 1563
constexpr int NB_I = (NUM_ITEM + KPB - 1) / KPB;      // 782
constexpr int GA   = 256;                             // hist/partition grid
constexpr int CH   = NUM_EDGES / GA;                  // 12500 (exact)

// ---------------------------------------------------------------------------
// bf16 helpers
// ---------------------------------------------------------------------------
__device__ __forceinline__ float bf2f(unsigned short u) {
  union { unsigned int i; float f; } v; v.i = (unsigned int)u << 16; return v.f;
}
__device__ __forceinline__ unsigned short f2bf(float x) {
  union { float f; unsigned int i; } v; v.f = x;
  unsigned int r = v.i + 0x7FFFu + ((v.i >> 16) & 1u);
  return (unsigned short)(r >> 16);
}

// ---------------------------------------------------------------------------
// Index dtype detection (int64 buffers have all-zero high words).
// ---------------------------------------------------------------------------
__global__ void k_detect(const void* eu, const void* ei, int* flag) {
  if (threadIdx.x == 0 && blockIdx.x == 0) {
    const int* a = (const int*)eu;
    const int* b = (const int*)ei;
    int any = 0;
    for (int i = 1; i < 64; i += 2) { any |= a[i]; any |= b[i]; }
    *flag = (any == 0) ? 1 : 0;  // 1 => int64 layout
  }
}

__device__ __forceinline__ int idx_at(const void* p, int e, int is64) {
  return is64 ? ((const int*)p)[2 * e] : ((const int*)p)[e];
}

// ---------------------------------------------------------------------------
// f32 -> bf16 table conversion
// user16: linear rows of 64 bf16.
// fused : per item row of 128 bf16, dim-interleaved [item_l, agg_l] pairs;
//         cvt writes the even (item) slots, k_agg_item writes the odd slots.
// ---------------------------------------------------------------------------
__global__ void k_cvt_user(const float* __restrict__ ue,
                           unsigned short* __restrict__ u16) {
  const int n4 = NUM_USER * DIM / 4;
  for (int t = blockIdx.x * blockDim.x + threadIdx.x; t < n4;
       t += gridDim.x * blockDim.x) {
    const float4 v = ((const float4*)ue)[t];
    ushort4 o;
    o.x = f2bf(v.x); o.y = f2bf(v.y); o.z = f2bf(v.z); o.w = f2bf(v.w);
    ((ushort4*)u16)[t] = o;
  }
}

__global__ void k_cvt_item(const float* __restrict__ ie,
                           unsigned short* __restrict__ fused) {
  const int n4 = NUM_ITEM * DIM / 4;
  for (int t = blockIdx.x * blockDim.x + threadIdx.x; t < n4;
       t += gridDim.x * blockDim.x) {
    const float4 v = ((const float4*)ie)[t];
    const int g = t * 4;
    const int row = g >> 6, l = g & 63;
    const size_t base = (size_t)row * 128 + 2 * l;
    fused[base + 0] = f2bf(v.x);
    fused[base + 2] = f2bf(v.y);
    fused[base + 4] = f2bf(v.z);
    fused[base + 6] = f2bf(v.w);
  }
}

// ---------------------------------------------------------------------------
// Bucket histogram: LDS-privatized, non-atomic per-block partial flush.
// partials overlays the pairs buffer (used before pairs are written).
// Layout: pu[key*GA + blk], pi at offset NB_U*GA.
// ---------------------------------------------------------------------------
__global__ void k_hist_part(const void* eu_p, const void* ei_p,
                            const int* __restrict__ flag,
                            int* __restrict__ partials) {
  __shared__ int hu[NB_U];
  __shared__ int hi_[NB_I];
  for (int t = threadIdx.x; t < NB_U; t += blockDim.x) hu[t] = 0;
  for (int t = threadIdx.x; t < NB_I; t += blockDim.x) hi_[t] = 0;
  __syncthreads();
  const int is64 = *flag;
  const int b = blockIdx.x;
  const int lo = b * CH, hiE = lo + CH;
  for (int e = lo + threadIdx.x; e < hiE; e += blockDim.x) {
    atomicAdd(&hu[idx_at(eu_p, e, is64) >> 6], 1);
    atomicAdd(&hi_[idx_at(ei_p, e, is64) >> 6], 1);
  }
  __syncthreads();
  int* pu = partials;
  int* pi = partials + (size_t)NB_U * GA;
  for (int t = threadIdx.x; t < NB_U; t += blockDim.x) pu[(size_t)t * GA + b] = hu[t];
  for (int t = threadIdx.x; t < NB_I; t += blockDim.x) pi[(size_t)t * GA + b] = hi_[t];
}

__global__ void k_hist_reduce(const int* __restrict__ partials,
                              int* __restrict__ gcnt_u, int* __restrict__ gcnt_i) {
  const int k = blockIdx.x * blockDim.x + threadIdx.x;
  if (k >= NB_U + NB_I) return;
  const int* base = (k < NB_U) ? partials + (size_t)k * GA
                               : partials + (size_t)NB_U * GA + (size_t)(k - NB_U) * GA;
  int s = 0;
  for (int b = 0; b < GA; ++b) s += base[b];
  if (k < NB_U) gcnt_u[k] = s;
  else          gcnt_i[k - NB_U] = s;
}

// ---------------------------------------------------------------------------
// Exclusive scans of bucket counts -> gbase (n+1 entries) and gcur (=gbase)
// ---------------------------------------------------------------------------
__device__ void scan_body(const int* __restrict__ in, int* __restrict__ out,
                          int* __restrict__ cur, int n) {
  __shared__ int part[1024];
  const int t = threadIdx.x;
  const int chunk = (n + 1023) >> 10;
  const int lo = min(t * chunk, n);
  const int hi = min(lo + chunk, n);
  int s = 0;
  for (int i = lo; i < hi; ++i) s += in[i];
  part[t] = s;
  __syncthreads();
  for (int d = 1; d < 1024; d <<= 1) {
    int v = (t >= d) ? part[t - d] : 0;
    __syncthreads();
    part[t] += v;
    __syncthreads();
  }
  int run = (t == 0) ? 0 : part[t - 1];
  for (int i = lo; i < hi; ++i) {
    int v = in[i];
    out[i] = run; cur[i] = run; run += v;
  }
  if (t == 1023) out[n] = part[1023];
}

__global__ void k_scan2(const int* cu, int* bu, int* curu,
                        const int* ci, int* bi, int* curi) {
  if (blockIdx.x == 0) scan_body(cu, bu, curu, NB_U);
  else                 scan_body(ci, bi, curi, NB_I);
}

// ---------------------------------------------------------------------------
// Partition edges into bucket-grouped packed pairs (local_key<<17 | value).
// Two-phase: LDS hist -> per-(block,bucket) reservation -> write.
// ---------------------------------------------------------------------------
__global__ void k_part(const void* key_p, const void* val_p,
                       const int* __restrict__ flag,
                       int* gcur, unsigned int* __restrict__ pairs, int NB) {
  __shared__ int hist[NB_U];
  __shared__ int base[NB_U];
  for (int t = threadIdx.x; t < NB; t += blockDim.x) hist[t] = 0;
  __syncthreads();
  const int is64 = *flag;
  const int blk = blockIdx.x;
  const int lo = blk * CH, hiE = lo + CH;
  for (int e = lo + threadIdx.x; e < hiE; e += blockDim.x)
    atomicAdd(&hist[idx_at(key_p, e, is64) >> 6], 1);
  __syncthreads();
  for (int t = threadIdx.x; t < NB; t += blockDim.x) {
    const int h = hist[t];
    base[t] = h ? atomicAdd(&gcur[t], h) : 0;
    hist[t] = 0;  // reuse as in-block cursor
  }
  __syncthreads();
  for (int e = lo + threadIdx.x; e < hiE; e += blockDim.x) {
    const int k = idx_at(key_p, e, is64);
    const int v = idx_at(val_p, e, is64);
    const int bkt = k >> 6;
    const int pos = base[bkt] + atomicAdd(&hist[bkt], 1);
    pairs[pos] = ((unsigned)(k & 63) << 17) | (unsigned)v;
  }
}

// ---------------------------------------------------------------------------
// Aggregation dir-I: one block per item bucket; 64x64 f32 accumulator in LDS.
// Writes the odd (agg) bf16 slots of the fused item table.
// ---------------------------------------------------------------------------
__global__ void k_agg_item(const unsigned short* __restrict__ user16,
                           const unsigned int* __restrict__ pairs,
                           const int* __restrict__ gbase_i,
                           unsigned short* __restrict__ fused) {
  __shared__ float acc[KPB * DIM];   // 16 KB
  __shared__ int cnt[KPB];
  for (int t = threadIdx.x; t < KPB * DIM; t += blockDim.x) acc[t] = 0.f;
  for (int t = threadIdx.x; t < KPB; t += blockDim.x) cnt[t] = 0;
  __syncthreads();
  const int lane = threadIdx.x & 63;
  const int wid  = threadIdx.x >> 6;            // 4 waves
  const int lo = gbase_i[blockIdx.x], hi = gbase_i[blockIdx.x + 1];
  for (int j = lo + wid * 4; j < hi; j += 16) {
    const int m = min(4, hi - j);
    float v[4]; int loc[4];
#pragma unroll
    for (int k = 0; k < 4; ++k) if (k < m) {
      const unsigned p = pairs[j + k];
      loc[k] = (int)(p >> 17);
      v[k] = bf2f(user16[(size_t)(p & 0x1FFFF) * DIM + lane]);
    }
#pragma unroll
    for (int k = 0; k < 4; ++k) if (k < m) {
      atomicAdd(&acc[loc[k] * DIM + lane], v[k]);
      if (lane == 0) atomicAdd(&cnt[loc[k]], 1);
    }
  }
  __syncthreads();
  const int item0 = blockIdx.x * KPB;
  for (int r = wid; r < KPB; r += 4) {
    const int item = item0 + r;
    if (item >= NUM_ITEM) continue;
    const float c = fmaxf((float)cnt[r], 1.f);
    fused[(size_t)item * 128 + 2 * lane + 1] = f2bf(acc[r * DIM + lane] / c);
  }
}

// ---------------------------------------------------------------------------
// Aggregation dir-U: one block per user bucket; two 64x64 f32 accumulators.
// One dword gather per pair from the fused table (item bf16 in lo, agg in hi).
// ---------------------------------------------------------------------------
__global__ void k_agg_user(const unsigned int* __restrict__ fused32,
                           const unsigned int* __restrict__ pairs,
                           const int* __restrict__ gbase_u,
                           float* __restrict__ out0, float* __restrict__ out1) {
  __shared__ float a0[KPB * DIM];    // 16 KB
  __shared__ float a1[KPB * DIM];    // 16 KB
  __shared__ int cnt[KPB];
  for (int t = threadIdx.x; t < KPB * DIM; t += blockDim.x) { a0[t] = 0.f; a1[t] = 0.f; }
  for (int t = threadIdx.x; t < KPB; t += blockDim.x) cnt[t] = 0;
  __syncthreads();
  const int lane = threadIdx.x & 63;
  const int wid  = threadIdx.x >> 6;
  const int lo = gbase_u[blockIdx.x], hi = gbase_u[blockIdx.x + 1];
  for (int j = lo + wid * 4; j < hi; j += 16) {
    const int m = min(4, hi - j);
    unsigned w[4]; int loc[4];
#pragma unroll
    for (int k = 0; k < 4; ++k) if (k < m) {
      const unsigned p = pairs[j + k];
      loc[k] = (int)(p >> 17);
      w[k] = fused32[(size_t)(p & 0x1FFFF) * DIM + lane];
    }
#pragma unroll
    for (int k = 0; k < 4; ++k) if (k < m) {
      atomicAdd(&a0[loc[k] * DIM + lane], bf2f((unsigned short)(w[k] & 0xFFFF)));
      atomicAdd(&a1[loc[k] * DIM + lane], bf2f((unsigned short)(w[k] >> 16)));
      if (lane == 0) atomicAdd(&cnt[loc[k]], 1);
    }
  }
  __syncthreads();
  const int u0 = blockIdx.x * KPB;
  for (int r = wid; r < KPB; r += 4) {
    const int u = u0 + r;
    if (u >= NUM_USER) continue;
    const float inv = 1.0f / fmaxf((float)cnt[r], 1.f);
    out0[(size_t)u * DIM + lane] = a0[r * DIM + lane] * inv;
    out1[(size_t)u * DIM + lane] = a1[r * DIM + lane] * inv;
  }
}

// ---------------------------------------------------------------------------
// Fallback (round-0 atomic path) if ws too small.
// ---------------------------------------------------------------------------
__global__ void k_scatter1(const float* __restrict__ user_emb,
                           const float* __restrict__ item_emb,
                           const void* eu_p, const void* ei_p,
                           const int* __restrict__ flag,
                           float* out0, float* item_sum,
                           float* cnt_user, float* cnt_item) {
  const int is64 = *flag;
  const int lane = threadIdx.x & (DIM - 1);
  const int sub  = threadIdx.x >> 6;
  const int epb  = blockDim.x >> 6;
  for (int e = blockIdx.x * epb + sub; e < NUM_EDGES; e += gridDim.x * epb) {
    const int eu = idx_at(eu_p, e, is64);
    const int ei = idx_at(ei_p, e, is64);
    atomicAdd(&out0[eu * DIM + lane], item_emb[ei * DIM + lane]);
    atomicAdd(&item_sum[ei * DIM + lane], user_emb[eu * DIM + lane]);
    if (lane == 0) {
      atomicAdd(&cnt_user[eu], 1.0f);
      atomicAdd(&cnt_item[ei], 1.0f);
    }
  }
}

__global__ void k_div_item(float* item_sum, const float* __restrict__ cnt_item) {
  const int n = NUM_ITEM * DIM;
  for (int t = blockIdx.x * blockDim.x + threadIdx.x; t < n;
       t += gridDim.x * blockDim.x)
    item_sum[t] /= fmaxf(cnt_item[t >> 6], 1.0f);
}

__global__ void k_scatter2(const float* __restrict__ item_agg,
                           const void* eu_p, const void* ei_p,
                           const int* __restrict__ flag, float* out1) {
  const int is64 = *flag;
  const int lane = threadIdx.x & (DIM - 1);
  const int sub  = threadIdx.x >> 6;
  const int epb  = blockDim.x >> 6;
  for (int e = blockIdx.x * epb + sub; e < NUM_EDGES; e += gridDim.x * epb) {
    const int eu = idx_at(eu_p, e, is64);
    const int ei = idx_at(ei_p, e, is64);
    atomicAdd(&out1[eu * DIM + lane], item_agg[ei * DIM + lane]);
  }
}

__global__ void k_finalize(float* out0, float* out1,
                           const float* __restrict__ cnt_user) {
  const int n = NUM_USER * DIM;
  for (int t = blockIdx.x * blockDim.x + threadIdx.x; t < n;
       t += gridDim.x * blockDim.x) {
    const float c = fmaxf(cnt_user[t >> 6], 1.0f);
    out0[t] /= c;
    out1[t] /= c;
  }
}

// ---------------------------------------------------------------------------
extern "C" void kernel_launch(void* const* d_in, const int* in_sizes, int n_in,
                              void* d_out, int out_size, void* d_ws, size_t ws_size,
                              hipStream_t stream) {
  const float* user_emb = (const float*)d_in[0];
  const float* item_emb = (const float*)d_in[1];
  const void*  eu_p     = d_in[2];
  const void*  ei_p     = d_in[3];

  float* out0 = (float*)d_out;
  float* out1 = out0 + (size_t)NUM_USER * DIM;

  // Workspace layout (u32 units), total ~38.43 MB
  const size_t o_pairs   = 0;                                    // 3.2M u32 (also partials overlay)
  const size_t o_user16  = o_pairs + NUM_EDGES;                  // 3.2M u32 (6.4M bf16)
  const size_t o_fused   = o_user16 + (size_t)NUM_USER * DIM / 2;// 3.2M u32 (6.4M bf16)
  const size_t o_gcnt_u  = o_fused + (size_t)NUM_ITEM * 128 / 2;
  const size_t o_gbase_u = o_gcnt_u + NB_U;
  const size_t o_gcur_u  = o_gbase_u + NB_U + 1;
  const size_t o_gcnt_i  = o_gcur_u + NB_U;
  const size_t o_gbase_i = o_gcnt_i + NB_I;
  const size_t o_gcur_i  = o_gbase_i + NB_I + 1;
  const size_t o_flag    = o_gcur_i + NB_I;
  const size_t need_bytes = (o_flag + 1) * 4;

  int* wsi = (int*)d_ws;
  float* wsf = (float*)d_ws;

  if (ws_size >= need_bytes) {
    unsigned int* pairs    = (unsigned int*)(wsi + o_pairs);
    int*          partials = wsi + o_pairs;                       // overlay
    unsigned short* user16 = (unsigned short*)(wsi + o_user16);
    unsigned short* fused  = (unsigned short*)(wsi + o_fused);
    unsigned int* fused32  = (unsigned int*)(wsi + o_fused);
    int* gcnt_u  = wsi + o_gcnt_u;
    int* gbase_u = wsi + o_gbase_u;
    int* gcur_u  = wsi + o_gcur_u;
    int* gcnt_i  = wsi + o_gcnt_i;
    int* gbase_i = wsi + o_gbase_i;
    int* gcur_i  = wsi + o_gcur_i;
    int* flag    = wsi + o_flag;

    k_detect<<<1, 64, 0, stream>>>(eu_p, ei_p, flag);
    k_hist_part<<<GA, 512, 0, stream>>>(eu_p, ei_p, flag, partials);
    k_hist_reduce<<<(NB_U + NB_I + 255) / 256, 256, 0, stream>>>(partials,
                                                                 gcnt_u, gcnt_i);
    k_scan2<<<2, 1024, 0, stream>>>(gcnt_u, gbase_u, gcur_u,
                                    gcnt_i, gbase_i, gcur_i);
    k_cvt_user<<<1024, 256, 0, stream>>>(user_emb, user16);
    k_cvt_item<<<512, 256, 0, stream>>>(item_emb, fused);

    // direction I: group by item, aggregate user embeddings
    k_part<<<GA, 512, 0, stream>>>(ei_p, eu_p, flag, gcur_i, pairs, NB_I);
    k_agg_item<<<NB_I, 256, 0, stream>>>(user16, pairs, gbase_i, fused);

    // direction U: group by user, aggregate fused (item | agg) rows
    k_part<<<GA, 512, 0, stream>>>(eu_p, ei_p, flag, gcur_u, pairs, NB_U);
    k_agg_user<<<NB_U, 256, 0, stream>>>(fused32, pairs, gbase_u, out0, out1);
  } else {
    // fallback: round-0 atomic path (needs ~13 MB)
    float* item_sum = wsf;
    float* cnt_user = wsf + (size_t)NUM_ITEM * DIM;
    float* cnt_item = cnt_user + NUM_USER;
    int*   flag     = (int*)(cnt_item + NUM_ITEM);
    const size_t used = ((size_t)NUM_ITEM * DIM + NUM_USER + NUM_ITEM + 1) * 4;

    hipMemsetAsync(d_out, 0, (size_t)out_size * sizeof(float), stream);
    hipMemsetAsync(d_ws, 0, used, stream);
    k_detect<<<1, 64, 0, stream>>>(eu_p, ei_p, flag);
    k_scatter1<<<4096, 256, 0, stream>>>(user_emb, item_emb, eu_p, ei_p, flag,
                                         out0, item_sum, cnt_user, cnt_item);
    k_div_item<<<2048, 256, 0, stream>>>(item_sum, cnt_item);
    k_scatter2<<<4096, 256, 0, stream>>>(item_sum, eu_p, ei_p, flag, out1);
    k_finalize<<<2048, 256, 0, stream>>>(out0, out1, cnt_user);
  }
}

// Round 5
// 419.325 us; speedup vs baseline: 9.2649x; 9.2649x over previous
//
#include <hip/hip_runtime.h>

constexpr int NUM_USER  = 100000;
constexpr int NUM_ITEM  = 50000;
constexpr int DIM       = 64;
constexpr int NUM_EDGES = 3200000;

constexpr int KPB   = 64;                             // keys per bucket
constexpr int NB_U  = (NUM_USER + KPB - 1) / KPB;     // 1563
constexpr int NB_I  = (NUM_ITEM + KPB - 1) / KPB;     // 782
constexpr int GA    = 256;                            // hist/partition grid
constexpr int CH    = NUM_EDGES / GA;                 // 12500 (exact)
constexpr int CHUNK = 4096;                           // pairs per LDS-CSR chunk

// ---------------------------------------------------------------------------
// bf16 helpers
// ---------------------------------------------------------------------------
__device__ __forceinline__ float bf2f(unsigned short u) {
  union { unsigned int i; float f; } v; v.i = (unsigned int)u << 16; return v.f;
}
__device__ __forceinline__ unsigned short f2bf(float x) {
  union { float f; unsigned int i; } v; v.f = x;
  unsigned int r = v.i + 0x7FFFu + ((v.i >> 16) & 1u);
  return (unsigned short)(r >> 16);
}

// ---------------------------------------------------------------------------
// Index dtype detection (int64 buffers have all-zero high words).
// ---------------------------------------------------------------------------
__global__ void k_detect(const void* eu, const void* ei, int* flag) {
  if (threadIdx.x == 0 && blockIdx.x == 0) {
    const int* a = (const int*)eu;
    const int* b = (const int*)ei;
    int any = 0;
    for (int i = 1; i < 64; i += 2) { any |= a[i]; any |= b[i]; }
    *flag = (any == 0) ? 1 : 0;  // 1 => int64 layout
  }
}

__device__ __forceinline__ int idx_at(const void* p, int e, int is64) {
  return is64 ? ((const int*)p)[2 * e] : ((const int*)p)[e];
}

// ---------------------------------------------------------------------------
// f32 -> bf16 tables.
// user16: linear rows of 64 bf16.
// fused : per item row of 128 bf16, dim-interleaved [item_l, agg_l]; cvt
//         writes even slots, k_agg_item writes odd slots.
// ---------------------------------------------------------------------------
__global__ void k_cvt_user(const float* __restrict__ ue,
                           unsigned short* __restrict__ u16) {
  const int n4 = NUM_USER * DIM / 4;
  for (int t = blockIdx.x * blockDim.x + threadIdx.x; t < n4;
       t += gridDim.x * blockDim.x) {
    const float4 v = ((const float4*)ue)[t];
    ushort4 o;
    o.x = f2bf(v.x); o.y = f2bf(v.y); o.z = f2bf(v.z); o.w = f2bf(v.w);
    ((ushort4*)u16)[t] = o;
  }
}

__global__ void k_cvt_item(const float* __restrict__ ie,
                           unsigned short* __restrict__ fused) {
  const int n4 = NUM_ITEM * DIM / 4;
  for (int t = blockIdx.x * blockDim.x + threadIdx.x; t < n4;
       t += gridDim.x * blockDim.x) {
    const float4 v = ((const float4*)ie)[t];
    const int g = t * 4;
    const int row = g >> 6, l = g & 63;
    const size_t base = (size_t)row * 128 + 2 * l;
    fused[base + 0] = f2bf(v.x);
    fused[base + 2] = f2bf(v.y);
    fused[base + 4] = f2bf(v.z);
    fused[base + 6] = f2bf(v.w);
  }
}

// ---------------------------------------------------------------------------
// Bucket histogram: LDS-privatized, per-block partial flush (no fp atomics).
// partials overlays the pairs buffer (used before pairs are written).
// ---------------------------------------------------------------------------
__global__ void k_hist_part(const void* eu_p, const void* ei_p,
                            const int* __restrict__ flag,
                            int* __restrict__ partials) {
  __shared__ int hu[NB_U];
  __shared__ int hi_[NB_I];
  for (int t = threadIdx.x; t < NB_U; t += blockDim.x) hu[t] = 0;
  for (int t = threadIdx.x; t < NB_I; t += blockDim.x) hi_[t] = 0;
  __syncthreads();
  const int is64 = *flag;
  const int b = blockIdx.x;
  const int lo = b * CH, hiE = lo + CH;
  for (int e = lo + threadIdx.x; e < hiE; e += blockDim.x) {
    atomicAdd(&hu[idx_at(eu_p, e, is64) >> 6], 1);
    atomicAdd(&hi_[idx_at(ei_p, e, is64) >> 6], 1);
  }
  __syncthreads();
  int* pu = partials;
  int* pi = partials + (size_t)NB_U * GA;
  for (int t = threadIdx.x; t < NB_U; t += blockDim.x) pu[(size_t)t * GA + b] = hu[t];
  for (int t = threadIdx.x; t < NB_I; t += blockDim.x) pi[(size_t)t * GA + b] = hi_[t];
}

__global__ void k_hist_reduce(const int* __restrict__ partials,
                              int* __restrict__ gcnt_u, int* __restrict__ gcnt_i) {
  const int k = blockIdx.x * blockDim.x + threadIdx.x;
  if (k >= NB_U + NB_I) return;
  const int* base = (k < NB_U) ? partials + (size_t)k * GA
                               : partials + (size_t)NB_U * GA + (size_t)(k - NB_U) * GA;
  int s = 0;
  for (int b = 0; b < GA; ++b) s += base[b];
  if (k < NB_U) gcnt_u[k] = s;
  else          gcnt_i[k - NB_U] = s;
}

// ---------------------------------------------------------------------------
// Exclusive scans of bucket counts
// ---------------------------------------------------------------------------
__device__ void scan_body(const int* __restrict__ in, int* __restrict__ out,
                          int* __restrict__ cur, int n) {
  __shared__ int part[1024];
  const int t = threadIdx.x;
  const int chunk = (n + 1023) >> 10;
  const int lo = min(t * chunk, n);
  const int hi = min(lo + chunk, n);
  int s = 0;
  for (int i = lo; i < hi; ++i) s += in[i];
  part[t] = s;
  __syncthreads();
  for (int d = 1; d < 1024; d <<= 1) {
    int v = (t >= d) ? part[t - d] : 0;
    __syncthreads();
    part[t] += v;
    __syncthreads();
  }
  int run = (t == 0) ? 0 : part[t - 1];
  for (int i = lo; i < hi; ++i) {
    int v = in[i];
    out[i] = run; cur[i] = run; run += v;
  }
  if (t == 1023) out[n] = part[1023];
}

__global__ void k_scan2(const int* cu, int* bu, int* curu,
                        const int* ci, int* bi, int* curi) {
  if (blockIdx.x == 0) scan_body(cu, bu, curu, NB_U);
  else                 scan_body(ci, bi, curi, NB_I);
}

// ---------------------------------------------------------------------------
// Partition edges into bucket-grouped packed pairs (local_key<<17 | value).
// ---------------------------------------------------------------------------
__global__ void k_part(const void* key_p, const void* val_p,
                       const int* __restrict__ flag,
                       int* gcur, unsigned int* __restrict__ pairs, int NB) {
  __shared__ int hist[NB_U];
  __shared__ int base[NB_U];
  for (int t = threadIdx.x; t < NB; t += blockDim.x) hist[t] = 0;
  __syncthreads();
  const int is64 = *flag;
  const int blk = blockIdx.x;
  const int lo = blk * CH, hiE = lo + CH;
  for (int e = lo + threadIdx.x; e < hiE; e += blockDim.x)
    atomicAdd(&hist[idx_at(key_p, e, is64) >> 6], 1);
  __syncthreads();
  for (int t = threadIdx.x; t < NB; t += blockDim.x) {
    const int h = hist[t];
    base[t] = h ? atomicAdd(&gcur[t], h) : 0;
    hist[t] = 0;  // reuse as in-block cursor
  }
  __syncthreads();
  for (int e = lo + threadIdx.x; e < hiE; e += blockDim.x) {
    const int k = idx_at(key_p, e, is64);
    const int v = idx_at(val_p, e, is64);
    const int bkt = k >> 6;
    const int pos = base[bkt] + atomicAdd(&hist[bkt], 1);
    pairs[pos] = ((unsigned)(k & 63) << 17) | (unsigned)v;
  }
}

// ---------------------------------------------------------------------------
// Bucket aggregation, dir-I: LDS-CSR per 4096-pair chunk, register accumulate.
// Each wave owns 16 contiguous local keys; lane = dim. No fp LDS atomics.
// ---------------------------------------------------------------------------
__global__ void k_agg_item(const unsigned short* __restrict__ user16,
                           const unsigned int* __restrict__ pairs,
                           const int* __restrict__ gbase_i,
                           unsigned short* __restrict__ fused) {
  __shared__ int sorted[CHUNK];
  __shared__ int hist[KPB], base[KPB], cur[KPB];
  const int tid = threadIdx.x;
  const int lane = tid & 63;
  const int wid = tid >> 6;
  const int lo = gbase_i[blockIdx.x], hi = gbase_i[blockIdx.x + 1];

  float s[16]; int cnt[16];
#pragma unroll
  for (int r = 0; r < 16; ++r) { s[r] = 0.f; cnt[r] = 0; }

  for (int clo = lo; clo < hi; clo += CHUNK) {
    const int csz = min(CHUNK, hi - clo);
    if (tid < KPB) hist[tid] = 0;
    __syncthreads();
    for (int j = tid; j < csz; j += 256)
      atomicAdd(&hist[pairs[clo + j] >> 17], 1);
    __syncthreads();
    if (tid < KPB) {
      int b = 0;
      for (int q = 0; q < tid; ++q) b += hist[q];
      base[tid] = b; cur[tid] = b;
    }
    __syncthreads();
    for (int j = tid; j < csz; j += 256) {
      const unsigned p = pairs[clo + j];
      const int slot = atomicAdd(&cur[p >> 17], 1);
      sorted[slot] = (int)(p & 0x1FFFF);
    }
    __syncthreads();
#pragma unroll
    for (int r = 0; r < 16; ++r) {
      const int key = wid * 16 + r;
      const int jlo = base[key], jhi = cur[key];
      cnt[r] += jhi - jlo;
      int j = jlo;
      for (; j + 3 < jhi; j += 4) {
        const float v0 = bf2f(user16[(size_t)sorted[j]     * DIM + lane]);
        const float v1 = bf2f(user16[(size_t)sorted[j + 1] * DIM + lane]);
        const float v2 = bf2f(user16[(size_t)sorted[j + 2] * DIM + lane]);
        const float v3 = bf2f(user16[(size_t)sorted[j + 3] * DIM + lane]);
        s[r] += (v0 + v1) + (v2 + v3);
      }
      for (; j < jhi; ++j)
        s[r] += bf2f(user16[(size_t)sorted[j] * DIM + lane]);
    }
    __syncthreads();
  }

  const int i0 = blockIdx.x * KPB;
#pragma unroll
  for (int r = 0; r < 16; ++r) {
    const int item = i0 + wid * 16 + r;
    if (item < NUM_ITEM) {
      const float c = fmaxf((float)cnt[r], 1.f);
      fused[(size_t)item * 128 + 2 * lane + 1] = f2bf(s[r] / c);
    }
  }
}

// ---------------------------------------------------------------------------
// Bucket aggregation, dir-U: same structure, one dword gather feeds both
// outputs (item bf16 in lo half, agg bf16 in hi half).
// ---------------------------------------------------------------------------
__global__ void k_agg_user(const unsigned int* __restrict__ fused32,
                           const unsigned int* __restrict__ pairs,
                           const int* __restrict__ gbase_u,
                           float* __restrict__ out0, float* __restrict__ out1) {
  __shared__ int sorted[CHUNK];
  __shared__ int hist[KPB], base[KPB], cur[KPB];
  const int tid = threadIdx.x;
  const int lane = tid & 63;
  const int wid = tid >> 6;
  const int lo = gbase_u[blockIdx.x], hi = gbase_u[blockIdx.x + 1];

  float s0[16], s1[16]; int cnt[16];
#pragma unroll
  for (int r = 0; r < 16; ++r) { s0[r] = 0.f; s1[r] = 0.f; cnt[r] = 0; }

  for (int clo = lo; clo < hi; clo += CHUNK) {
    const int csz = min(CHUNK, hi - clo);
    if (tid < KPB) hist[tid] = 0;
    __syncthreads();
    for (int j = tid; j < csz; j += 256)
      atomicAdd(&hist[pairs[clo + j] >> 17], 1);
    __syncthreads();
    if (tid < KPB) {
      int b = 0;
      for (int q = 0; q < tid; ++q) b += hist[q];
      base[tid] = b; cur[tid] = b;
    }
    __syncthreads();
    for (int j = tid; j < csz; j += 256) {
      const unsigned p = pairs[clo + j];
      const int slot = atomicAdd(&cur[p >> 17], 1);
      sorted[slot] = (int)(p & 0x1FFFF);
    }
    __syncthreads();
#pragma unroll
    for (int r = 0; r < 16; ++r) {
      const int key = wid * 16 + r;
      const int jlo = base[key], jhi = cur[key];
      cnt[r] += jhi - jlo;
      int j = jlo;
      for (; j + 3 < jhi; j += 4) {
        const unsigned w0 = fused32[(size_t)sorted[j]     * DIM + lane];
        const unsigned w1 = fused32[(size_t)sorted[j + 1] * DIM + lane];
        const unsigned w2 = fused32[(size_t)sorted[j + 2] * DIM + lane];
        const unsigned w3 = fused32[(size_t)sorted[j + 3] * DIM + lane];
        s0[r] += (bf2f((unsigned short)(w0 & 0xFFFF)) + bf2f((unsigned short)(w1 & 0xFFFF)))
               + (bf2f((unsigned short)(w2 & 0xFFFF)) + bf2f((unsigned short)(w3 & 0xFFFF)));
        s1[r] += (bf2f((unsigned short)(w0 >> 16)) + bf2f((unsigned short)(w1 >> 16)))
               + (bf2f((unsigned short)(w2 >> 16)) + bf2f((unsigned short)(w3 >> 16)));
      }
      for (; j < jhi; ++j) {
        const unsigned w = fused32[(size_t)sorted[j] * DIM + lane];
        s0[r] += bf2f((unsigned short)(w & 0xFFFF));
        s1[r] += bf2f((unsigned short)(w >> 16));
      }
    }
    __syncthreads();
  }

  const int u0 = blockIdx.x * KPB;
#pragma unroll
  for (int r = 0; r < 16; ++r) {
    const int u = u0 + wid * 16 + r;
    if (u < NUM_USER) {
      const float inv = 1.0f / fmaxf((float)cnt[r], 1.f);
      out0[(size_t)u * DIM + lane] = s0[r] * inv;
      out1[(size_t)u * DIM + lane] = s1[r] * inv;
    }
  }
}

// ---------------------------------------------------------------------------
// Fallback (round-0 atomic path) if ws too small.
// ---------------------------------------------------------------------------
__global__ void k_scatter1(const float* __restrict__ user_emb,
                           const float* __restrict__ item_emb,
                           const void* eu_p, const void* ei_p,
                           const int* __restrict__ flag,
                           float* out0, float* item_sum,
                           float* cnt_user, float* cnt_item) {
  const int is64 = *flag;
  const int lane = threadIdx.x & (DIM - 1);
  const int sub  = threadIdx.x >> 6;
  const int epb  = blockDim.x >> 6;
  for (int e = blockIdx.x * epb + sub; e < NUM_EDGES; e += gridDim.x * epb) {
    const int eu = idx_at(eu_p, e, is64);
    const int ei = idx_at(ei_p, e, is64);
    atomicAdd(&out0[eu * DIM + lane], item_emb[ei * DIM + lane]);
    atomicAdd(&item_sum[ei * DIM + lane], user_emb[eu * DIM + lane]);
    if (lane == 0) {
      atomicAdd(&cnt_user[eu], 1.0f);
      atomicAdd(&cnt_item[ei], 1.0f);
    }
  }
}

__global__ void k_div_item(float* item_sum, const float* __restrict__ cnt_item) {
  const int n = NUM_ITEM * DIM;
  for (int t = blockIdx.x * blockDim.x + threadIdx.x; t < n;
       t += gridDim.x * blockDim.x)
    item_sum[t] /= fmaxf(cnt_item[t >> 6], 1.0f);
}

__global__ void k_scatter2(const float* __restrict__ item_agg,
                           const void* eu_p, const void* ei_p,
                           const int* __restrict__ flag, float* out1) {
  const int is64 = *flag;
  const int lane = threadIdx.x & (DIM - 1);
  const int sub  = threadIdx.x >> 6;
  const int epb  = blockDim.x >> 6;
  for (int e = blockIdx.x * epb + sub; e < NUM_EDGES; e += gridDim.x * epb) {
    const int eu = idx_at(eu_p, e, is64);
    const int ei = idx_at(ei_p, e, is64);
    atomicAdd(&out1[eu * DIM + lane], item_agg[ei * DIM + lane]);
  }
}

__global__ void k_finalize(float* out0, float* out1,
                           const float* __restrict__ cnt_user) {
  const int n = NUM_USER * DIM;
  for (int t = blockIdx.x * blockDim.x + threadIdx.x; t < n;
       t += gridDim.x * blockDim.x) {
    const float c = fmaxf(cnt_user[t >> 6], 1.0f);
    out0[t] /= c;
    out1[t] /= c;
  }
}

// ---------------------------------------------------------------------------
extern "C" void kernel_launch(void* const* d_in, const int* in_sizes, int n_in,
                              void* d_out, int out_size, void* d_ws, size_t ws_size,
                              hipStream_t stream) {
  const float* user_emb = (const float*)d_in[0];
  const float* item_emb = (const float*)d_in[1];
  const void*  eu_p     = d_in[2];
  const void*  ei_p     = d_in[3];

  float* out0 = (float*)d_out;
  float* out1 = out0 + (size_t)NUM_USER * DIM;

  // Workspace layout (u32 units), ~38.4 MB (proven available in R2-R4)
  const size_t o_pairs   = 0;                                    // 3.2M u32 (+partials overlay)
  const size_t o_user16  = o_pairs + NUM_EDGES;                  // 3.2M u32
  const size_t o_fused   = o_user16 + (size_t)NUM_USER * DIM / 2;// 3.2M u32
  const size_t o_gcnt_u  = o_fused + (size_t)NUM_ITEM * 128 / 2;
  const size_t o_gbase_u = o_gcnt_u + NB_U;
  const size_t o_gcur_u  = o_gbase_u + NB_U + 1;
  const size_t o_gcnt_i  = o_gcur_u + NB_U;
  const size_t o_gbase_i = o_gcnt_i + NB_I;
  const size_t o_gcur_i  = o_gbase_i + NB_I + 1;
  const size_t o_flag    = o_gcur_i + NB_I;
  const size_t need_bytes = (o_flag + 1) * 4;

  int* wsi = (int*)d_ws;
  float* wsf = (float*)d_ws;

  if (ws_size >= need_bytes) {
    unsigned int* pairs    = (unsigned int*)(wsi + o_pairs);
    int*          partials = wsi + o_pairs;                       // overlay
    unsigned short* user16 = (unsigned short*)(wsi + o_user16);
    unsigned short* fused  = (unsigned short*)(wsi + o_fused);
    unsigned int* fused32  = (unsigned int*)(wsi + o_fused);
    int* gcnt_u  = wsi + o_gcnt_u;
    int* gbase_u = wsi + o_gbase_u;
    int* gcur_u  = wsi + o_gcur_u;
    int* gcnt_i  = wsi + o_gcnt_i;
    int* gbase_i = wsi + o_gbase_i;
    int* gcur_i  = wsi + o_gcur_i;
    int* flag    = wsi + o_flag;

    k_detect<<<1, 64, 0, stream>>>(eu_p, ei_p, flag);
    k_hist_part<<<GA, 512, 0, stream>>>(eu_p, ei_p, flag, partials);
    k_hist_reduce<<<(NB_U + NB_I + 255) / 256, 256, 0, stream>>>(partials,
                                                                 gcnt_u, gcnt_i);
    k_scan2<<<2, 1024, 0, stream>>>(gcnt_u, gbase_u, gcur_u,
                                    gcnt_i, gbase_i, gcur_i);
    k_cvt_user<<<1024, 256, 0, stream>>>(user_emb, user16);
    k_cvt_item<<<512, 256, 0, stream>>>(item_emb, fused);

    // direction I: group by item, aggregate user embeddings -> fused odd slots
    k_part<<<GA, 512, 0, stream>>>(ei_p, eu_p, flag, gcur_i, pairs, NB_I);
    k_agg_item<<<NB_I, 256, 0, stream>>>(user16, pairs, gbase_i, fused);

    // direction U: group by user, aggregate fused rows -> out0, out1
    k_part<<<GA, 512, 0, stream>>>(eu_p, ei_p, flag, gcur_u, pairs, NB_U);
    k_agg_user<<<NB_U, 256, 0, stream>>>(fused32, pairs, gbase_u, out0, out1);
  } else {
    // fallback: round-0 atomic path (needs ~13 MB)
    float* item_sum = wsf;
    float* cnt_user = wsf + (size_t)NUM_ITEM * DIM;
    float* cnt_item = cnt_user + NUM_USER;
    int*   flag     = (int*)(cnt_item + NUM_ITEM);
    const size_t used = ((size_t)NUM_ITEM * DIM + NUM_USER + NUM_ITEM + 1) * 4;

    hipMemsetAsync(d_out, 0, (size_t)out_size * sizeof(float), stream);
    hipMemsetAsync(d_ws, 0, used, stream);
    k_detect<<<1, 64, 0, stream>>>(eu_p, ei_p, flag);
    k_scatter1<<<4096, 256, 0, stream>>>(user_emb, item_emb, eu_p, ei_p, flag,
                                         out0, item_sum, cnt_user, cnt_item);
    k_div_item<<<2048, 256, 0, stream>>>(item_sum, cnt_item);
    k_scatter2<<<4096, 256, 0, stream>>>(item_sum, eu_p, ei_p, flag, out1);
    k_finalize<<<2048, 256, 0, stream>>>(out0, out1, cnt_user);
  }
}

// Round 6
// 324.914 us; speedup vs baseline: 11.9570x; 1.2906x over previous
//
#include <hip/hip_runtime.h>

constexpr int NUM_USER  = 100000;
constexpr int NUM_ITEM  = 50000;
constexpr int DIM       = 64;
constexpr int NUM_EDGES = 3200000;

constexpr int KPB   = 64;                             // keys per bucket
constexpr int NB_U  = (NUM_USER + KPB - 1) / KPB;     // 1563
constexpr int NB_I  = (NUM_ITEM + KPB - 1) / KPB;     // 782
constexpr int GA    = 256;                            // hist/partition grid
constexpr int CH    = NUM_EDGES / GA;                 // 12500 (exact)
constexpr int CHUNK = 4096;                           // pairs per LDS-CSR chunk
constexpr int HKEY  = 32;                             // keys per agg half-block

// ---------------------------------------------------------------------------
// bf16 helpers
// ---------------------------------------------------------------------------
__device__ __forceinline__ float bf2f(unsigned short u) {
  union { unsigned int i; float f; } v; v.i = (unsigned int)u << 16; return v.f;
}
__device__ __forceinline__ unsigned short f2bf(float x) {
  union { float f; unsigned int i; } v; v.f = x;
  unsigned int r = v.i + 0x7FFFu + ((v.i >> 16) & 1u);
  return (unsigned short)(r >> 16);
}

// ---------------------------------------------------------------------------
// Index dtype detection (int64 buffers have all-zero high words).
// ---------------------------------------------------------------------------
__global__ void k_detect(const void* eu, const void* ei, int* flag) {
  if (threadIdx.x == 0 && blockIdx.x == 0) {
    const int* a = (const int*)eu;
    const int* b = (const int*)ei;
    int any = 0;
    for (int i = 1; i < 64; i += 2) { any |= a[i]; any |= b[i]; }
    *flag = (any == 0) ? 1 : 0;  // 1 => int64 layout
  }
}

__device__ __forceinline__ int idx_at(const void* p, int e, int is64) {
  return is64 ? ((const int*)p)[2 * e] : ((const int*)p)[e];
}

// ---------------------------------------------------------------------------
// f32 -> bf16 tables.
// user16: linear rows of 64 bf16.
// fused : per item row of 128 bf16, dim-interleaved [item_l, agg_l]; cvt
//         writes even slots, k_agg_item writes odd slots.
// ---------------------------------------------------------------------------
__global__ void k_cvt_user(const float* __restrict__ ue,
                           unsigned short* __restrict__ u16) {
  const int n4 = NUM_USER * DIM / 4;
  for (int t = blockIdx.x * blockDim.x + threadIdx.x; t < n4;
       t += gridDim.x * blockDim.x) {
    const float4 v = ((const float4*)ue)[t];
    ushort4 o;
    o.x = f2bf(v.x); o.y = f2bf(v.y); o.z = f2bf(v.z); o.w = f2bf(v.w);
    ((ushort4*)u16)[t] = o;
  }
}

__global__ void k_cvt_item(const float* __restrict__ ie,
                           unsigned short* __restrict__ fused) {
  const int n4 = NUM_ITEM * DIM / 4;
  for (int t = blockIdx.x * blockDim.x + threadIdx.x; t < n4;
       t += gridDim.x * blockDim.x) {
    const float4 v = ((const float4*)ie)[t];
    const int g = t * 4;
    const int row = g >> 6, l = g & 63;
    const size_t base = (size_t)row * 128 + 2 * l;
    fused[base + 0] = f2bf(v.x);
    fused[base + 2] = f2bf(v.y);
    fused[base + 4] = f2bf(v.z);
    fused[base + 6] = f2bf(v.w);
  }
}

// ---------------------------------------------------------------------------
// Bucket histogram: LDS-privatized, per-block partial flush (no fp atomics).
// partials overlays the pairs buffer (used before pairs are written).
// ---------------------------------------------------------------------------
__global__ void k_hist_part(const void* eu_p, const void* ei_p,
                            const int* __restrict__ flag,
                            int* __restrict__ partials) {
  __shared__ int hu[NB_U];
  __shared__ int hi_[NB_I];
  for (int t = threadIdx.x; t < NB_U; t += blockDim.x) hu[t] = 0;
  for (int t = threadIdx.x; t < NB_I; t += blockDim.x) hi_[t] = 0;
  __syncthreads();
  const int is64 = *flag;
  const int b = blockIdx.x;
  const int lo = b * CH, hiE = lo + CH;
  for (int e = lo + threadIdx.x; e < hiE; e += blockDim.x) {
    atomicAdd(&hu[idx_at(eu_p, e, is64) >> 6], 1);
    atomicAdd(&hi_[idx_at(ei_p, e, is64) >> 6], 1);
  }
  __syncthreads();
  int* pu = partials;
  int* pi = partials + (size_t)NB_U * GA;
  for (int t = threadIdx.x; t < NB_U; t += blockDim.x) pu[(size_t)t * GA + b] = hu[t];
  for (int t = threadIdx.x; t < NB_I; t += blockDim.x) pi[(size_t)t * GA + b] = hi_[t];
}

__global__ void k_hist_reduce(const int* __restrict__ partials,
                              int* __restrict__ gcnt_u, int* __restrict__ gcnt_i) {
  const int k = blockIdx.x * blockDim.x + threadIdx.x;
  if (k >= NB_U + NB_I) return;
  const int* base = (k < NB_U) ? partials + (size_t)k * GA
                               : partials + (size_t)NB_U * GA + (size_t)(k - NB_U) * GA;
  int s = 0;
  for (int b = 0; b < GA; ++b) s += base[b];
  if (k < NB_U) gcnt_u[k] = s;
  else          gcnt_i[k - NB_U] = s;
}

// ---------------------------------------------------------------------------
// Exclusive scans of bucket counts
// ---------------------------------------------------------------------------
__device__ void scan_body(const int* __restrict__ in, int* __restrict__ out,
                          int* __restrict__ cur, int n) {
  __shared__ int part[1024];
  const int t = threadIdx.x;
  const int chunk = (n + 1023) >> 10;
  const int lo = min(t * chunk, n);
  const int hi = min(lo + chunk, n);
  int s = 0;
  for (int i = lo; i < hi; ++i) s += in[i];
  part[t] = s;
  __syncthreads();
  for (int d = 1; d < 1024; d <<= 1) {
    int v = (t >= d) ? part[t - d] : 0;
    __syncthreads();
    part[t] += v;
    __syncthreads();
  }
  int run = (t == 0) ? 0 : part[t - 1];
  for (int i = lo; i < hi; ++i) {
    int v = in[i];
    out[i] = run; cur[i] = run; run += v;
  }
  if (t == 1023) out[n] = part[1023];
}

__global__ void k_scan2(const int* cu, int* bu, int* curu,
                        const int* ci, int* bi, int* curi) {
  if (blockIdx.x == 0) scan_body(cu, bu, curu, NB_U);
  else                 scan_body(ci, bi, curi, NB_I);
}

// ---------------------------------------------------------------------------
// Partition edges into bucket-grouped packed pairs (local_key<<17 | value).
// ---------------------------------------------------------------------------
__global__ void k_part(const void* key_p, const void* val_p,
                       const int* __restrict__ flag,
                       int* gcur, unsigned int* __restrict__ pairs, int NB) {
  __shared__ int hist[NB_U];
  __shared__ int base[NB_U];
  for (int t = threadIdx.x; t < NB; t += blockDim.x) hist[t] = 0;
  __syncthreads();
  const int is64 = *flag;
  const int blk = blockIdx.x;
  const int lo = blk * CH, hiE = lo + CH;
  for (int e = lo + threadIdx.x; e < hiE; e += blockDim.x)
    atomicAdd(&hist[idx_at(key_p, e, is64) >> 6], 1);
  __syncthreads();
  for (int t = threadIdx.x; t < NB; t += blockDim.x) {
    const int h = hist[t];
    base[t] = h ? atomicAdd(&gcur[t], h) : 0;
    hist[t] = 0;  // reuse as in-block cursor
  }
  __syncthreads();
  for (int e = lo + threadIdx.x; e < hiE; e += blockDim.x) {
    const int k = idx_at(key_p, e, is64);
    const int v = idx_at(val_p, e, is64);
    const int bkt = k >> 6;
    const int pos = base[bkt] + atomicAdd(&hist[bkt], 1);
    pairs[pos] = ((unsigned)(k & 63) << 17) | (unsigned)v;
  }
}

// ---------------------------------------------------------------------------
// Bucket aggregation, dir-I. 2 blocks per bucket, each owns 32 local keys
// (half = blockIdx&1). LDS-CSR over the half's entries; each wave owns 8
// keys, register accumulate, 4-wide ILP. No fp LDS atomics.
// ---------------------------------------------------------------------------
__global__ __launch_bounds__(256, 8)
void k_agg_item(const unsigned short* __restrict__ user16,
                const unsigned int* __restrict__ pairs,
                const int* __restrict__ gbase_i,
                unsigned short* __restrict__ fused) {
  __shared__ int sorted[CHUNK];
  __shared__ int hist[HKEY], base[HKEY], cur[HKEY];
  const int tid = threadIdx.x;
  const int lane = tid & 63;
  const int wid = tid >> 6;
  const int bucket = blockIdx.x >> 1;
  const int key0 = (blockIdx.x & 1) * HKEY;
  const int lo = gbase_i[bucket], hi = gbase_i[bucket + 1];

  float s[8]; int cnt[8];
#pragma unroll
  for (int r = 0; r < 8; ++r) { s[r] = 0.f; cnt[r] = 0; }

  for (int clo = lo; clo < hi; clo += CHUNK) {
    const int csz = min(CHUNK, hi - clo);
    if (tid < HKEY) hist[tid] = 0;
    __syncthreads();
    for (int j = tid; j < csz; j += 256) {
      const int k = (int)(pairs[clo + j] >> 17) - key0;
      if ((unsigned)k < HKEY) atomicAdd(&hist[k], 1);
    }
    __syncthreads();
    if (tid < HKEY) {
      int b = 0;
      for (int q = 0; q < tid; ++q) b += hist[q];
      base[tid] = b; cur[tid] = b;
    }
    __syncthreads();
    for (int j = tid; j < csz; j += 256) {
      const unsigned p = pairs[clo + j];
      const int k = (int)(p >> 17) - key0;
      if ((unsigned)k < HKEY) {
        const int slot = atomicAdd(&cur[k], 1);
        sorted[slot] = (int)(p & 0x1FFFF);
      }
    }
    __syncthreads();
#pragma unroll
    for (int r = 0; r < 8; ++r) {
      const int key = wid * 8 + r;
      const int jlo = base[key], jhi = cur[key];
      cnt[r] += jhi - jlo;
      int j = jlo;
      for (; j + 3 < jhi; j += 4) {
        const float v0 = bf2f(user16[(size_t)sorted[j]     * DIM + lane]);
        const float v1 = bf2f(user16[(size_t)sorted[j + 1] * DIM + lane]);
        const float v2 = bf2f(user16[(size_t)sorted[j + 2] * DIM + lane]);
        const float v3 = bf2f(user16[(size_t)sorted[j + 3] * DIM + lane]);
        s[r] += (v0 + v1) + (v2 + v3);
      }
      for (; j < jhi; ++j)
        s[r] += bf2f(user16[(size_t)sorted[j] * DIM + lane]);
    }
    __syncthreads();
  }

  const int i0 = bucket * KPB + key0;
#pragma unroll
  for (int r = 0; r < 8; ++r) {
    const int item = i0 + wid * 8 + r;
    if (item < NUM_ITEM) {
      const float c = fmaxf((float)cnt[r], 1.f);
      fused[(size_t)item * 128 + 2 * lane + 1] = f2bf(s[r] / c);
    }
  }
}

// ---------------------------------------------------------------------------
// Bucket aggregation, dir-U: same split structure; one dword gather feeds
// both outputs (item bf16 in lo half, agg bf16 in hi half).
// ---------------------------------------------------------------------------
__global__ __launch_bounds__(256, 8)
void k_agg_user(const unsigned int* __restrict__ fused32,
                const unsigned int* __restrict__ pairs,
                const int* __restrict__ gbase_u,
                float* __restrict__ out0, float* __restrict__ out1) {
  __shared__ int sorted[CHUNK];
  __shared__ int hist[HKEY], base[HKEY], cur[HKEY];
  const int tid = threadIdx.x;
  const int lane = tid & 63;
  const int wid = tid >> 6;
  const int bucket = blockIdx.x >> 1;
  const int key0 = (blockIdx.x & 1) * HKEY;
  const int lo = gbase_u[bucket], hi = gbase_u[bucket + 1];

  float s0[8], s1[8]; int cnt[8];
#pragma unroll
  for (int r = 0; r < 8; ++r) { s0[r] = 0.f; s1[r] = 0.f; cnt[r] = 0; }

  for (int clo = lo; clo < hi; clo += CHUNK) {
    const int csz = min(CHUNK, hi - clo);
    if (tid < HKEY) hist[tid] = 0;
    __syncthreads();
    for (int j = tid; j < csz; j += 256) {
      const int k = (int)(pairs[clo + j] >> 17) - key0;
      if ((unsigned)k < HKEY) atomicAdd(&hist[k], 1);
    }
    __syncthreads();
    if (tid < HKEY) {
      int b = 0;
      for (int q = 0; q < tid; ++q) b += hist[q];
      base[tid] = b; cur[tid] = b;
    }
    __syncthreads();
    for (int j = tid; j < csz; j += 256) {
      const unsigned p = pairs[clo + j];
      const int k = (int)(p >> 17) - key0;
      if ((unsigned)k < HKEY) {
        const int slot = atomicAdd(&cur[k], 1);
        sorted[slot] = (int)(p & 0x1FFFF);
      }
    }
    __syncthreads();
#pragma unroll
    for (int r = 0; r < 8; ++r) {
      const int key = wid * 8 + r;
      const int jlo = base[key], jhi = cur[key];
      cnt[r] += jhi - jlo;
      int j = jlo;
      for (; j + 3 < jhi; j += 4) {
        const unsigned w0 = fused32[(size_t)sorted[j]     * DIM + lane];
        const unsigned w1 = fused32[(size_t)sorted[j + 1] * DIM + lane];
        const unsigned w2 = fused32[(size_t)sorted[j + 2] * DIM + lane];
        const unsigned w3 = fused32[(size_t)sorted[j + 3] * DIM + lane];
        s0[r] += (bf2f((unsigned short)(w0 & 0xFFFF)) + bf2f((unsigned short)(w1 & 0xFFFF)))
               + (bf2f((unsigned short)(w2 & 0xFFFF)) + bf2f((unsigned short)(w3 & 0xFFFF)));
        s1[r] += (bf2f((unsigned short)(w0 >> 16)) + bf2f((unsigned short)(w1 >> 16)))
               + (bf2f((unsigned short)(w2 >> 16)) + bf2f((unsigned short)(w3 >> 16)));
      }
      for (; j < jhi; ++j) {
        const unsigned w = fused32[(size_t)sorted[j] * DIM + lane];
        s0[r] += bf2f((unsigned short)(w & 0xFFFF));
        s1[r] += bf2f((unsigned short)(w >> 16));
      }
    }
    __syncthreads();
  }

  const int u0 = bucket * KPB + key0;
#pragma unroll
  for (int r = 0; r < 8; ++r) {
    const int u = u0 + wid * 8 + r;
    if (u < NUM_USER) {
      const float inv = 1.0f / fmaxf((float)cnt[r], 1.f);
      out0[(size_t)u * DIM + lane] = s0[r] * inv;
      out1[(size_t)u * DIM + lane] = s1[r] * inv;
    }
  }
}

// ---------------------------------------------------------------------------
// Fallback (round-0 atomic path) if ws too small.
// ---------------------------------------------------------------------------
__global__ void k_scatter1(const float* __restrict__ user_emb,
                           const float* __restrict__ item_emb,
                           const void* eu_p, const void* ei_p,
                           const int* __restrict__ flag,
                           float* out0, float* item_sum,
                           float* cnt_user, float* cnt_item) {
  const int is64 = *flag;
  const int lane = threadIdx.x & (DIM - 1);
  const int sub  = threadIdx.x >> 6;
  const int epb  = blockDim.x >> 6;
  for (int e = blockIdx.x * epb + sub; e < NUM_EDGES; e += gridDim.x * epb) {
    const int eu = idx_at(eu_p, e, is64);
    const int ei = idx_at(ei_p, e, is64);
    atomicAdd(&out0[eu * DIM + lane], item_emb[ei * DIM + lane]);
    atomicAdd(&item_sum[ei * DIM + lane], user_emb[eu * DIM + lane]);
    if (lane == 0) {
      atomicAdd(&cnt_user[eu], 1.0f);
      atomicAdd(&cnt_item[ei], 1.0f);
    }
  }
}

__global__ void k_div_item(float* item_sum, const float* __restrict__ cnt_item) {
  const int n = NUM_ITEM * DIM;
  for (int t = blockIdx.x * blockDim.x + threadIdx.x; t < n;
       t += gridDim.x * blockDim.x)
    item_sum[t] /= fmaxf(cnt_item[t >> 6], 1.0f);
}

__global__ void k_scatter2(const float* __restrict__ item_agg,
                           const void* eu_p, const void* ei_p,
                           const int* __restrict__ flag, float* out1) {
  const int is64 = *flag;
  const int lane = threadIdx.x & (DIM - 1);
  const int sub  = threadIdx.x >> 6;
  const int epb  = blockDim.x >> 6;
  for (int e = blockIdx.x * epb + sub; e < NUM_EDGES; e += gridDim.x * epb) {
    const int eu = idx_at(eu_p, e, is64);
    const int ei = idx_at(ei_p, e, is64);
    atomicAdd(&out1[eu * DIM + lane], item_agg[ei * DIM + lane]);
  }
}

__global__ void k_finalize(float* out0, float* out1,
                           const float* __restrict__ cnt_user) {
  const int n = NUM_USER * DIM;
  for (int t = blockIdx.x * blockDim.x + threadIdx.x; t < n;
       t += gridDim.x * blockDim.x) {
    const float c = fmaxf(cnt_user[t >> 6], 1.0f);
    out0[t] /= c;
    out1[t] /= c;
  }
}

// ---------------------------------------------------------------------------
extern "C" void kernel_launch(void* const* d_in, const int* in_sizes, int n_in,
                              void* d_out, int out_size, void* d_ws, size_t ws_size,
                              hipStream_t stream) {
  const float* user_emb = (const float*)d_in[0];
  const float* item_emb = (const float*)d_in[1];
  const void*  eu_p     = d_in[2];
  const void*  ei_p     = d_in[3];

  float* out0 = (float*)d_out;
  float* out1 = out0 + (size_t)NUM_USER * DIM;

  // Workspace layout (u32 units), ~38.4 MB (proven available in R2-R5)
  const size_t o_pairs   = 0;                                    // 3.2M u32 (+partials overlay)
  const size_t o_user16  = o_pairs + NUM_EDGES;                  // 3.2M u32
  const size_t o_fused   = o_user16 + (size_t)NUM_USER * DIM / 2;// 3.2M u32
  const size_t o_gcnt_u  = o_fused + (size_t)NUM_ITEM * 128 / 2;
  const size_t o_gbase_u = o_gcnt_u + NB_U;
  const size_t o_gcur_u  = o_gbase_u + NB_U + 1;
  const size_t o_gcnt_i  = o_gcur_u + NB_U;
  const size_t o_gbase_i = o_gcnt_i + NB_I;
  const size_t o_gcur_i  = o_gbase_i + NB_I + 1;
  const size_t o_flag    = o_gcur_i + NB_I;
  const size_t need_bytes = (o_flag + 1) * 4;

  int* wsi = (int*)d_ws;
  float* wsf = (float*)d_ws;

  if (ws_size >= need_bytes) {
    unsigned int* pairs    = (unsigned int*)(wsi + o_pairs);
    int*          partials = wsi + o_pairs;                       // overlay
    unsigned short* user16 = (unsigned short*)(wsi + o_user16);
    unsigned short* fused  = (unsigned short*)(wsi + o_fused);
    unsigned int* fused32  = (unsigned int*)(wsi + o_fused);
    int* gcnt_u  = wsi + o_gcnt_u;
    int* gbase_u = wsi + o_gbase_u;
    int* gcur_u  = wsi + o_gcur_u;
    int* gcnt_i  = wsi + o_gcnt_i;
    int* gbase_i = wsi + o_gbase_i;
    int* gcur_i  = wsi + o_gcur_i;
    int* flag    = wsi + o_flag;

    k_detect<<<1, 64, 0, stream>>>(eu_p, ei_p, flag);
    k_hist_part<<<GA, 512, 0, stream>>>(eu_p, ei_p, flag, partials);
    k_hist_reduce<<<(NB_U + NB_I + 255) / 256, 256, 0, stream>>>(partials,
                                                                 gcnt_u, gcnt_i);
    k_scan2<<<2, 1024, 0, stream>>>(gcnt_u, gbase_u, gcur_u,
                                    gcnt_i, gbase_i, gcur_i);
    k_cvt_user<<<1024, 256, 0, stream>>>(user_emb, user16);
    k_cvt_item<<<512, 256, 0, stream>>>(item_emb, fused);

    // direction I: group by item, aggregate user embeddings -> fused odd slots
    k_part<<<GA, 512, 0, stream>>>(ei_p, eu_p, flag, gcur_i, pairs, NB_I);
    k_agg_item<<<NB_I * 2, 256, 0, stream>>>(user16, pairs, gbase_i, fused);

    // direction U: group by user, aggregate fused rows -> out0, out1
    k_part<<<GA, 512, 0, stream>>>(eu_p, ei_p, flag, gcur_u, pairs, NB_U);
    k_agg_user<<<NB_U * 2, 256, 0, stream>>>(fused32, pairs, gbase_u, out0, out1);
  } else {
    // fallback: round-0 atomic path (needs ~13 MB)
    float* item_sum = wsf;
    float* cnt_user = wsf + (size_t)NUM_ITEM * DIM;
    float* cnt_item = cnt_user + NUM_USER;
    int*   flag     = (int*)(cnt_item + NUM_ITEM);
    const size_t used = ((size_t)NUM_ITEM * DIM + NUM_USER + NUM_ITEM + 1) * 4;

    hipMemsetAsync(d_out, 0, (size_t)out_size * sizeof(float), stream);
    hipMemsetAsync(d_ws, 0, used, stream);
    k_detect<<<1, 64, 0, stream>>>(eu_p, ei_p, flag);
    k_scatter1<<<4096, 256, 0, stream>>>(user_emb, item_emb, eu_p, ei_p, flag,
                                         out0, item_sum, cnt_user, cnt_item);
    k_div_item<<<2048, 256, 0, stream>>>(item_sum, cnt_item);
    k_scatter2<<<4096, 256, 0, stream>>>(item_sum, eu_p, ei_p, flag, out1);
    k_finalize<<<2048, 256, 0, stream>>>(out0, out1, cnt_user);
  }
}